// Round 9
// baseline (319.138 us; speedup 1.0000x reference)
//
#include <hip/hip_runtime.h>
#include <hip/hip_bf16.h>

#define HD   64
#define SEQ  2048
#define NB   256
#define TWOH 128
#define NCH  32   // SEQ / 64

typedef float v4f __attribute__((ext_vector_type(4)));

// ---- DPP wave-total: sum across 64 lanes, broadcast via lane 63 ----
template <int CTRL>
__device__ __forceinline__ float dpp_add(float x) {
    int y = __builtin_amdgcn_update_dpp(0, __builtin_bit_cast(int, x),
                                        CTRL, 0xF, 0xF, true);
    return x + __builtin_bit_cast(float, y);
}

__device__ __forceinline__ float wave_total(float x) {
    x = dpp_add<0x111>(x);   // row_shr:1
    x = dpp_add<0x112>(x);   // row_shr:2
    x = dpp_add<0x114>(x);   // row_shr:4
    x = dpp_add<0x118>(x);   // row_shr:8
    x = dpp_add<0x142>(x);   // row_bcast:15
    x = dpp_add<0x143>(x);   // row_bcast:31 -> lane 63 has full sum
    return __builtin_bit_cast(float,
        __builtin_amdgcn_readlane(__builtin_bit_cast(int, x), 63));
}

__device__ __forceinline__ float bcastf(float v, int l) {
    return __builtin_bit_cast(float,
        __builtin_amdgcn_readlane(__builtin_bit_cast(int, v), l));
}

__device__ __forceinline__ float hsum4(v4f a) {
    return (a.x + a.y) + (a.z + a.w);
}

// f32 data read as bf16 at even 16-bit halves -> huge/NaN values. Wave-level
// (__any over 64 lanes); lane-indexed so all 4 waves get identical results.
__device__ __forceinline__ bool detect_bf16(const void* embed, int lane) {
    const unsigned short* u = (const unsigned short*)embed;
    int bad = 0;
    for (int i = 2 * lane; i < 4096; i += 128) {
        float v = __uint_as_float(((unsigned int)u[i]) << 16);
        if (!(fabsf(v) < 1e4f)) bad = 1;
    }
    return !__any(bad);
}

template <bool BF>
__device__ __forceinline__ float ldf(const void* p, int i) {
    if (BF) return __bfloat162float(((const __hip_bfloat16*)p)[i]);
    return ((const float*)p)[i];
}

// Per-wave encoder: wave `wid` encodes tokens 16wid..16wid+16 into LDS
// tables. Cross-lane data moves through per-wave scratch; same-wave DS
// ordering + explicit lgkmcnt(0)/"memory" barriers (R4 lesson) make the
// write->read transitions safe without __syncthreads.
template <bool BF>
__device__ void encode16(int wid, int lane, const void* embed, const void* w1,
                         const void* b1, const void* w2, const void* b2,
                         const void* ln_g, const void* ln_b, const void* wk,
                         const void* wvp, const void* wq,
                         float* __restrict__ k_lds, float* __restrict__ v_lds,
                         float* __restrict__ q_lds, float* __restrict__ thr2_lds,
                         float* __restrict__ shh, float* __restrict__ shu) {
    #pragma unroll 1
    for (int it = 0; it < 16; ++it) {
        const int t = wid * 16 + it;
        float h = ldf<BF>(embed, t * HD + lane);
        shh[lane] = h;
        asm volatile("s_waitcnt lgkmcnt(0)" ::: "memory");

        // FFN1: u = relu(h @ w1 + b1); lane -> outputs (lane, lane+64)
        float a0 = 0.f, a1 = 0.f, a2 = 0.f, a3 = 0.f;
        #pragma unroll 16
        for (int j = 0; j < HD; j += 2) {
            float h0 = shh[j], h1 = shh[j + 1];
            a0 = fmaf(h0, ldf<BF>(w1, j * TWOH + lane), a0);
            a1 = fmaf(h0, ldf<BF>(w1, j * TWOH + lane + HD), a1);
            a2 = fmaf(h1, ldf<BF>(w1, (j + 1) * TWOH + lane), a2);
            a3 = fmaf(h1, ldf<BF>(w1, (j + 1) * TWOH + lane + HD), a3);
        }
        shu[lane]      = fmaxf(a0 + a2 + ldf<BF>(b1, lane), 0.f);
        shu[lane + HD] = fmaxf(a1 + a3 + ldf<BF>(b1, lane + HD), 0.f);
        asm volatile("s_waitcnt lgkmcnt(0)" ::: "memory");

        // FFN2 + residual
        float f0 = 0.f, f1 = 0.f, f2 = 0.f, f3 = 0.f;
        #pragma unroll 16
        for (int e = 0; e < TWOH; e += 4) {
            f0 = fmaf(shu[e + 0], ldf<BF>(w2, (e + 0) * HD + lane), f0);
            f1 = fmaf(shu[e + 1], ldf<BF>(w2, (e + 1) * HD + lane), f1);
            f2 = fmaf(shu[e + 2], ldf<BF>(w2, (e + 2) * HD + lane), f2);
            f3 = fmaf(shu[e + 3], ldf<BF>(w2, (e + 3) * HD + lane), f3);
        }
        float y = h + (f0 + f1) + (f2 + f3) + ldf<BF>(b2, lane);

        // LayerNorm (eps 1e-5) via in-wave DPP reductions
        float mu  = wave_total(y) * 0.015625f;
        float dvv = y - mu;
        float var = wave_total(dvv * dvv) * 0.015625f;
        float hn  = fmaf(dvv * (1.f / sqrtf(var + 1e-5f)), ldf<BF>(ln_g, lane),
                         ldf<BF>(ln_b, lane));

        shh[lane] = hn;                      // program order: FFN1 reads done
        asm volatile("s_waitcnt lgkmcnt(0)" ::: "memory");

        // k/v/q projections
        float k0 = 0.f, k1 = 0.f, v0 = 0.f, v1 = 0.f, q0 = 0.f, q1 = 0.f;
        #pragma unroll 16
        for (int j = 0; j < HD; j += 2) {
            float h0 = shh[j], h1 = shh[j + 1];
            k0 = fmaf(h0, ldf<BF>(wk, j * HD + lane), k0);
            v0 = fmaf(h0, ldf<BF>(wvp, j * HD + lane), v0);
            q0 = fmaf(h0, ldf<BF>(wq, j * HD + lane), q0);
            k1 = fmaf(h1, ldf<BF>(wk, (j + 1) * HD + lane), k1);
            v1 = fmaf(h1, ldf<BF>(wvp, (j + 1) * HD + lane), v1);
            q1 = fmaf(h1, ldf<BF>(wq, (j + 1) * HD + lane), q1);
        }
        float k = k0 + k1, v = v0 + v1, q = q0 + q1;
        float nk = sqrtf(wave_total(k * k));
        k /= fmaxf(nk, 1e-12f);              // k / max(||k||, NORM_EPS)
        float nv2 = wave_total(v * v);

        k_lds[t * HD + lane] = k;
        v_lds[t * HD + lane] = v;
        q_lds[t * HD + lane] = q;
        if (lane == 0) thr2_lds[t] = 0.16f * nv2;   // (0.4*||v||)^2
    }
}

// Single fused kernel: 256 blocks (one per batch) x 256 threads (4 waves,
// one per SIMD). Phase 1: each block redundantly encodes all 64 tokens
// (wave w -> tokens 16w..16w+16) into LDS (~10 µs, weights L2-hot; removes
// the precompute launch + ~90 µs gap). Phase 2: R8's verified fire loop —
// wave w owns components [16w,16w+16) of every token's residual dv; fires
// broadcast delta quarters from own-lane registers (16 readlanes), 12
// pk_fma, and combine ||dv||^2 partials via ping-pong LDS with ONE barrier.
__global__ __launch_bounds__(256, 1) void fused_kernel(
    const int* __restrict__ x, const void* embed, const void* w1,
    const void* b1, const void* w2, const void* b2, const void* ln_g,
    const void* ln_b, const void* wk, const void* wvp, const void* wq,
    const void* wo, const void* bo, void* __restrict__ out) {
    const int b = blockIdx.x, tid = threadIdx.x;
    const int wid = tid >> 6, lane = tid & 63;
    __shared__ __align__(16) float k_lds[4096];
    __shared__ __align__(16) float g_lds[4096];
    __shared__ __align__(16) float v_lds[4096];
    __shared__ __align__(16) float q_lds[4096];
    __shared__ int   tok_lds[SEQ];
    __shared__ float thr2_lds[64];
    __shared__ float pbuf[2][4][64];     // ping-pong nd2 partials
    __shared__ __align__(16) float rd_lds[64];
    __shared__ float sh_h[4][HD];        // per-wave encoder scratch
    __shared__ float sh_u[4][TWOH];

    // stage token stream (coalesced over 256 threads)
    const int* xr = x + b * SEQ;
    #pragma unroll
    for (int c = 0; c < 8; ++c) tok_lds[c * 256 + tid] = xr[c * 256 + tid];

    // Phase 1: encoder (per-wave, no cross-wave deps)
    const bool bf = detect_bf16(embed, lane);
    if (bf)
        encode16<true>(wid, lane, embed, w1, b1, w2, b2, ln_g, ln_b, wk, wvp,
                       wq, k_lds, v_lds, q_lds, thr2_lds, sh_h[wid], sh_u[wid]);
    else
        encode16<false>(wid, lane, embed, w1, b1, w2, b2, ln_g, ln_b, wk, wvp,
                        wq, k_lds, v_lds, q_lds, thr2_lds, sh_h[wid], sh_u[wid]);
    __syncthreads();                     // k/v/q/thr2/tok visible to all

    const float thr2 = thr2_lds[lane];

    // k_lane full row into registers (one-time; bank conflicts accepted)
    v4f kreg[16];
    #pragma unroll
    for (int i = 0; i < 16; ++i)
        kreg[i] = *(const v4f*)&k_lds[lane * HD + i * 4];

    // cq_lane = k_lane . q_{last token}  (q row = uniform reads -> broadcast)
    const int tl = tok_lds[SEQ - 1];
    v4f cacc = {0.f, 0.f, 0.f, 0.f};
    #pragma unroll
    for (int i = 0; i < 16; ++i) {
        const float* qp = &q_lds[tl * HD + i * 4];
        v4f qv = {qp[0], qp[1], qp[2], qp[3]};
        cacc = __builtin_elementwise_fma(qv, kreg[i], cacc);
    }
    const float cq = hsum4(cacc);

    // G build: wave w computes rows [16w,16w+16): G[t][lane] = k_t . k_lane
    #pragma unroll 1
    for (int t0 = 0; t0 < 16; ++t0) {
        const int t = wid * 16 + t0;
        const float* kt = &k_lds[t * HD];    // uniform -> LDS broadcast
        v4f a = {0.f, 0.f, 0.f, 0.f};
        #pragma unroll
        for (int i = 0; i < 16; ++i) {
            const v4f kv = *(const v4f*)&kt[i * 4];
            a = __builtin_elementwise_fma(kv, kreg[i], a);
        }
        g_lds[t * HD + lane] = hsum4(a);
    }

    // dv quarter = v_lane[16wid..16wid+16); R = 0; partial nd2
    v4f dv[4], R[4];
    v4f acc = {0.f, 0.f, 0.f, 0.f};
    #pragma unroll
    for (int i = 0; i < 4; ++i) {
        dv[i] = *(const v4f*)&v_lds[lane * HD + wid * 16 + i * 4];
        R[i]  = (v4f){0.f, 0.f, 0.f, 0.f};
        acc   = __builtin_elementwise_fma(dv[i], dv[i], acc);
    }
    pbuf[0][wid][lane] = hsum4(acc);
    int pp = 1;
    __syncthreads();                       // g_lds + pbuf[0] visible
    float nd2 = ((pbuf[0][0][lane] + pbuf[0][1][lane]) +
                 (pbuf[0][2][lane] + pbuf[0][3][lane]));
    unsigned long long fireset = __ballot(nd2 > thr2);

    // Phase 2: fire loop (R8-verified)
    int chunk = tok_lds[lane];
    #pragma unroll 1
    for (int c = 0; c < NCH; ++c) {
        int nxt = 0;
        if (c + 1 < NCH) nxt = tok_lds[(c + 1) * 64 + lane];
        unsigned long long pend = __ballot((int)((fireset >> chunk) & 1ull));
        while (pend) {
            const int s = __builtin_ctzll(pend);
            const int t = __builtin_amdgcn_readlane(chunk, s);
            const float g   = g_lds[t * HD + lane];
            const float cqt = bcastf(cq, t);
            const v4f gs  = {-g, -g, -g, -g};
            const v4f cqs = {cqt, cqt, cqt, cqt};
            v4f q4 = {0.f, 0.f, 0.f, 0.f};
            #pragma unroll
            for (int i = 0; i < 4; ++i) {
                v4f sve;                           // delta_t quarter (own regs)
                sve.x = bcastf(dv[i].x, t);
                sve.y = bcastf(dv[i].y, t);
                sve.z = bcastf(dv[i].z, t);
                sve.w = bcastf(dv[i].w, t);
                dv[i] = __builtin_elementwise_fma(gs, sve, dv[i]);
                R[i]  = __builtin_elementwise_fma(cqs, sve, R[i]);
                q4    = __builtin_elementwise_fma(dv[i], dv[i], q4);
            }
            pbuf[pp][wid][lane] = hsum4(q4);
            __syncthreads();                       // single barrier per fire
            nd2 = ((pbuf[pp][0][lane] + pbuf[pp][1][lane]) +
                   (pbuf[pp][2][lane] + pbuf[pp][3][lane]));
            pp ^= 1;                               // ping-pong: no 2nd barrier
            fireset = __ballot(nd2 > thr2);
            const unsigned long long above =
                (s >= 63) ? 0ull : (~0ull << (s + 1));
            pend = __ballot((int)((fireset >> chunk) & 1ull)) & above;
        }
        chunk = nxt;
    }

    // read = relu(R): wave w holds components [16wid..16wid+16) in each lane
    if (lane == 0) {
        #pragma unroll
        for (int i = 0; i < 4; ++i) {
            v4f r = R[i];
            r.x = fmaxf(r.x, 0.f); r.y = fmaxf(r.y, 0.f);
            r.z = fmaxf(r.z, 0.f); r.w = fmaxf(r.w, 0.f);
            *(v4f*)&rd_lds[wid * 16 + i * 4] = r;
        }
    }
    __syncthreads();

    // out[b][c] = sum_j rd[j] * wo[j][c] + bo[c]  — wave 0 only (lane = c)
    if (wid == 0) {
        if (bf) {
            float acc2 = __bfloat162float(((const __hip_bfloat16*)bo)[lane]);
            #pragma unroll 8
            for (int j = 0; j < HD; ++j)
                acc2 = fmaf(rd_lds[j],
                    __bfloat162float(((const __hip_bfloat16*)wo)[j * HD + lane]),
                    acc2);
            ((__hip_bfloat16*)out)[b * HD + lane] = __float2bfloat16(acc2);
        } else {
            float acc2 = ((const float*)bo)[lane];
            #pragma unroll 8
            for (int j = 0; j < HD; ++j)
                acc2 = fmaf(rd_lds[j], ((const float*)wo)[j * HD + lane], acc2);
            ((float*)out)[b * HD + lane] = acc2;
        }
    }
}

extern "C" void kernel_launch(void* const* d_in, const int* in_sizes, int n_in,
                              void* d_out, int out_size, void* d_ws, size_t ws_size,
                              hipStream_t stream) {
    const int* x      = (const int*)d_in[0];
    const void* embed = d_in[1];
    const void* w1    = d_in[2];
    const void* b1    = d_in[3];
    const void* w2    = d_in[4];
    const void* b2    = d_in[5];
    const void* ln_g  = d_in[6];
    const void* ln_b  = d_in[7];
    const void* wk    = d_in[8];
    const void* wvp   = d_in[9];
    const void* wq    = d_in[10];
    const void* wo    = d_in[11];
    const void* bo    = d_in[12];

    fused_kernel<<<NB, 256, 0, stream>>>(x, embed, w1, b1, w2, b2, ln_g, ln_b,
                                         wk, wvp, wq, wo, bo, d_out);
}

// Round 10
// 283.461 us; speedup vs baseline: 1.1259x; 1.1259x over previous
//
#include <hip/hip_runtime.h>
#include <hip/hip_bf16.h>

#define HD   64
#define SEQ  2048
#define NB   256
#define TWOH 128
#define NCH  32   // SEQ / 64

typedef float v4f __attribute__((ext_vector_type(4)));

// ---- DPP wave-total: sum across 64 lanes, broadcast via lane 63 ----
template <int CTRL>
__device__ __forceinline__ float dpp_add(float x) {
    int y = __builtin_amdgcn_update_dpp(0, __builtin_bit_cast(int, x),
                                        CTRL, 0xF, 0xF, true);
    return x + __builtin_bit_cast(float, y);
}

__device__ __forceinline__ float wave_total(float x) {
    x = dpp_add<0x111>(x);   // row_shr:1
    x = dpp_add<0x112>(x);   // row_shr:2
    x = dpp_add<0x114>(x);   // row_shr:4
    x = dpp_add<0x118>(x);   // row_shr:8
    x = dpp_add<0x142>(x);   // row_bcast:15
    x = dpp_add<0x143>(x);   // row_bcast:31 -> lane 63 has full sum
    return __builtin_bit_cast(float,
        __builtin_amdgcn_readlane(__builtin_bit_cast(int, x), 63));
}

__device__ __forceinline__ float bcastf(float v, int l) {
    return __builtin_bit_cast(float,
        __builtin_amdgcn_readlane(__builtin_bit_cast(int, v), l));
}

__device__ __forceinline__ float hsum4(v4f a) {
    return (a.x + a.y) + (a.z + a.w);
}

// f32 data read as bf16 at even 16-bit halves -> huge/NaN values. Wave-level
// (__any over 64 lanes); lane-indexed so all 4 waves get identical results.
__device__ __forceinline__ bool detect_bf16(const void* embed, int lane) {
    const unsigned short* u = (const unsigned short*)embed;
    int bad = 0;
    for (int i = 2 * lane; i < 4096; i += 128) {
        float v = __uint_as_float(((unsigned int)u[i]) << 16);
        if (!(fabsf(v) < 1e4f)) bad = 1;
    }
    return !__any(bad);
}

template <bool BF>
__device__ __forceinline__ float ldf(const void* p, int i) {
    if (BF) return __bfloat162float(((const __hip_bfloat16*)p)[i]);
    return ((const float*)p)[i];
}

#define LGKM_BARRIER() asm volatile("s_waitcnt lgkmcnt(0)" ::: "memory")

// Weight-streaming per-wave encoder: wave `wid` encodes its 16 tokens
// SIMULTANEOUSLY (token dim in registers, feature dim in lanes). Each weight
// element is loaded ONCE per wave and reused by 16 register accumulators —
// ~480 VMEM instrs/wave vs ~7200 for the R9 token-serial version (the +68 µs
// regression). Broadcast operands come from token-major LDS rows via
// uniform-address v4f reads (HW broadcast, conflict-free). Cross-op LDS
// transitions guarded by lgkmcnt(0)+"memory" (R4 lesson).
// Writes k_lds/v_lds/thr2; q computed ONLY for token tl -> qrow.
template <bool BF>
__device__ void encode_stream(int wid, int lane, int tl, const void* embed,
                              const void* w1, const void* b1, const void* w2,
                              const void* b2, const void* ln_g, const void* ln_b,
                              const void* wk, const void* wvp, const void* wq,
                              float* __restrict__ k_lds, float* __restrict__ v_lds,
                              float* __restrict__ thr2_lds,
                              float* __restrict__ qrow,
                              float* __restrict__ hb,     // [16*64] per wave
                              float* __restrict__ ub) {   // [16*64] per wave
    const int tbase = wid * 16;
    float h[16];
    #pragma unroll
    for (int it = 0; it < 16; ++it) {
        h[it] = ldf<BF>(embed, (tbase + it) * HD + lane);
        hb[it * HD + lane] = h[it];          // 2-way bank = free
    }
    LGKM_BARRIER();

    // FFN1: u[it][e] = relu(sum_j h[it][j]*w1[j][e] + b1[e]); e = lane, lane+64
    float u0[16], u1[16];
    #pragma unroll
    for (int it = 0; it < 16; ++it) { u0[it] = 0.f; u1[it] = 0.f; }
    #pragma unroll 1
    for (int j4 = 0; j4 < 16; ++j4) {
        const int j = j4 * 4;
        float wa0 = ldf<BF>(w1, (j + 0) * TWOH + lane);
        float wb0 = ldf<BF>(w1, (j + 0) * TWOH + lane + HD);
        float wa1 = ldf<BF>(w1, (j + 1) * TWOH + lane);
        float wb1 = ldf<BF>(w1, (j + 1) * TWOH + lane + HD);
        float wa2 = ldf<BF>(w1, (j + 2) * TWOH + lane);
        float wb2 = ldf<BF>(w1, (j + 2) * TWOH + lane + HD);
        float wa3 = ldf<BF>(w1, (j + 3) * TWOH + lane);
        float wb3 = ldf<BF>(w1, (j + 3) * TWOH + lane + HD);
        #pragma unroll
        for (int it = 0; it < 16; ++it) {
            const v4f hj = *(const v4f*)&hb[it * HD + j];   // uniform bcast
            u0[it] = fmaf(hj.x, wa0, u0[it]); u1[it] = fmaf(hj.x, wb0, u1[it]);
            u0[it] = fmaf(hj.y, wa1, u0[it]); u1[it] = fmaf(hj.y, wb1, u1[it]);
            u0[it] = fmaf(hj.z, wa2, u0[it]); u1[it] = fmaf(hj.z, wb2, u1[it]);
            u0[it] = fmaf(hj.w, wa3, u0[it]); u1[it] = fmaf(hj.w, wb3, u1[it]);
        }
    }
    const float bb0 = ldf<BF>(b1, lane), bb1 = ldf<BF>(b1, lane + HD);
    #pragma unroll
    for (int it = 0; it < 16; ++it) {
        u0[it] = fmaxf(u0[it] + bb0, 0.f);
        u1[it] = fmaxf(u1[it] + bb1, 0.f);
    }

    // FFN2 in two e-passes through the shared u-buffer (halves LDS scratch)
    float f[16];
    #pragma unroll
    for (int it = 0; it < 16; ++it) f[it] = 0.f;
    LGKM_BARRIER();                          // hb reads done before ub writes? (ub separate; hb reused later)
    #pragma unroll
    for (int it = 0; it < 16; ++it) ub[it * HD + lane] = u0[it];
    LGKM_BARRIER();
    #pragma unroll 1
    for (int e4 = 0; e4 < 16; ++e4) {
        const int e = e4 * 4;
        float w0 = ldf<BF>(w2, (e + 0) * HD + lane);
        float w1v = ldf<BF>(w2, (e + 1) * HD + lane);
        float w2v = ldf<BF>(w2, (e + 2) * HD + lane);
        float w3 = ldf<BF>(w2, (e + 3) * HD + lane);
        #pragma unroll
        for (int it = 0; it < 16; ++it) {
            const v4f ue = *(const v4f*)&ub[it * HD + e];    // uniform bcast
            f[it] = fmaf(ue.x, w0, f[it]);
            f[it] = fmaf(ue.y, w1v, f[it]);
            f[it] = fmaf(ue.z, w2v, f[it]);
            f[it] = fmaf(ue.w, w3, f[it]);
        }
    }
    LGKM_BARRIER();                          // pass-A reads before overwrite
    #pragma unroll
    for (int it = 0; it < 16; ++it) ub[it * HD + lane] = u1[it];
    LGKM_BARRIER();
    #pragma unroll 1
    for (int e4 = 0; e4 < 16; ++e4) {
        const int e = e4 * 4;
        float w0 = ldf<BF>(w2, (HD + e + 0) * HD + lane);
        float w1v = ldf<BF>(w2, (HD + e + 1) * HD + lane);
        float w2v = ldf<BF>(w2, (HD + e + 2) * HD + lane);
        float w3 = ldf<BF>(w2, (HD + e + 3) * HD + lane);
        #pragma unroll
        for (int it = 0; it < 16; ++it) {
            const v4f ue = *(const v4f*)&ub[it * HD + e];    // uniform bcast
            f[it] = fmaf(ue.x, w0, f[it]);
            f[it] = fmaf(ue.y, w1v, f[it]);
            f[it] = fmaf(ue.z, w2v, f[it]);
            f[it] = fmaf(ue.w, w3, f[it]);
        }
    }
    const float b2v = ldf<BF>(b2, lane);
    const float lg = ldf<BF>(ln_g, lane), lb = ldf<BF>(ln_b, lane);

    // LayerNorm per token + restage hn into hb
    LGKM_BARRIER();                          // hb FFN1 reads complete
    #pragma unroll 1
    for (int it = 0; it < 16; ++it) {
        float y = h[it] + f[it] + b2v;
        float mu  = wave_total(y) * 0.015625f;
        float dvv = y - mu;
        float var = wave_total(dvv * dvv) * 0.015625f;
        float hn  = fmaf(dvv * (1.f / sqrtf(var + 1e-5f)), lg, lb);
        hb[it * HD + lane] = hn;
    }
    LGKM_BARRIER();

    // k/v projections (streamed); q only for token tl
    float k[16], v[16];
    #pragma unroll
    for (int it = 0; it < 16; ++it) { k[it] = 0.f; v[it] = 0.f; }
    #pragma unroll 1
    for (int j4 = 0; j4 < 16; ++j4) {
        const int j = j4 * 4;
        float ka = ldf<BF>(wk, (j + 0) * HD + lane);
        float kb = ldf<BF>(wk, (j + 1) * HD + lane);
        float kc = ldf<BF>(wk, (j + 2) * HD + lane);
        float kd = ldf<BF>(wk, (j + 3) * HD + lane);
        float va = ldf<BF>(wvp, (j + 0) * HD + lane);
        float vb = ldf<BF>(wvp, (j + 1) * HD + lane);
        float vc = ldf<BF>(wvp, (j + 2) * HD + lane);
        float vd = ldf<BF>(wvp, (j + 3) * HD + lane);
        #pragma unroll
        for (int it = 0; it < 16; ++it) {
            const v4f hj = *(const v4f*)&hb[it * HD + j];    // uniform bcast
            k[it] = fmaf(hj.x, ka, k[it]); v[it] = fmaf(hj.x, va, v[it]);
            k[it] = fmaf(hj.y, kb, k[it]); v[it] = fmaf(hj.y, vb, v[it]);
            k[it] = fmaf(hj.z, kc, k[it]); v[it] = fmaf(hj.z, vc, v[it]);
            k[it] = fmaf(hj.w, kd, k[it]); v[it] = fmaf(hj.w, vd, v[it]);
        }
    }
    #pragma unroll 1
    for (int it = 0; it < 16; ++it) {
        const int t = tbase + it;
        float nk = sqrtf(wave_total(k[it] * k[it]));
        float kn = k[it] / fmaxf(nk, 1e-12f);       // k / max(||k||, NORM_EPS)
        float nv2 = wave_total(v[it] * v[it]);
        k_lds[t * HD + lane] = kn;
        v_lds[t * HD + lane] = v[it];
        if (lane == 0) thr2_lds[t] = 0.16f * nv2;   // (0.4*||v||)^2
    }
    if (tl >= tbase && tl < tbase + 16) {           // wave-uniform
        float q = 0.f;
        const int it = tl - tbase;
        #pragma unroll
        for (int j4 = 0; j4 < 16; ++j4) {
            const v4f hj = *(const v4f*)&hb[it * HD + j4 * 4];
            q = fmaf(hj.x, ldf<BF>(wq, (j4 * 4 + 0) * HD + lane), q);
            q = fmaf(hj.y, ldf<BF>(wq, (j4 * 4 + 1) * HD + lane), q);
            q = fmaf(hj.z, ldf<BF>(wq, (j4 * 4 + 2) * HD + lane), q);
            q = fmaf(hj.w, ldf<BF>(wq, (j4 * 4 + 3) * HD + lane), q);
        }
        qrow[lane] = q;
    }
}

// Single fused kernel: 256 blocks (one per batch) x 4 waves (one per SIMD).
// Phase 1: weight-streaming encoder (above). Phase 2: R8-verified fire loop —
// wave w owns components [16w,16w+16) of every token's residual dv; fires
// broadcast delta quarters from own-lane registers (16 readlanes), 12 pk_fma,
// combine ||dv||^2 partials via ping-pong LDS with ONE barrier per fire.
__global__ __launch_bounds__(256, 1) void fused_kernel(
    const int* __restrict__ x, const void* embed, const void* w1,
    const void* b1, const void* w2, const void* b2, const void* ln_g,
    const void* ln_b, const void* wk, const void* wvp, const void* wq,
    const void* wo, const void* bo, void* __restrict__ out) {
    const int b = blockIdx.x, tid = threadIdx.x;
    const int wid = tid >> 6, lane = tid & 63;
    __shared__ __align__(16) float k_lds[4096];
    __shared__ __align__(16) float v_lds[4096];
    __shared__ __align__(16) float gu_lds[4096];  // encoder u-buf, then G
    __shared__ __align__(16) float hbuf[4096];    // encoder h-buf (per wave 1K)
    __shared__ int   tok_lds[SEQ];
    __shared__ float thr2_lds[64];
    __shared__ float qrow[64];
    __shared__ float pbuf[2][4][64];     // ping-pong nd2 partials
    __shared__ __align__(16) float rd_lds[64];

    // stage token stream (coalesced over 256 threads)
    const int* xr = x + b * SEQ;
    #pragma unroll
    for (int c = 0; c < 8; ++c) tok_lds[c * 256 + tid] = xr[c * 256 + tid];
    const int tl = xr[SEQ - 1];          // uniform scalar load (no barrier dep)

    // Phase 1: encoder
    const bool bf = detect_bf16(embed, lane);
    if (bf)
        encode_stream<true>(wid, lane, tl, embed, w1, b1, w2, b2, ln_g, ln_b,
                            wk, wvp, wq, k_lds, v_lds, thr2_lds, qrow,
                            &hbuf[wid * 1024], &gu_lds[wid * 1024]);
    else
        encode_stream<false>(wid, lane, tl, embed, w1, b1, w2, b2, ln_g, ln_b,
                             wk, wvp, wq, k_lds, v_lds, thr2_lds, qrow,
                             &hbuf[wid * 1024], &gu_lds[wid * 1024]);
    __syncthreads();                     // k/v/thr2/qrow visible; u-buf dead

    const float thr2 = thr2_lds[lane];

    // k_lane full row into registers (one-time; row-read conflicts accepted)
    v4f kreg[16];
    #pragma unroll
    for (int i = 0; i < 16; ++i)
        kreg[i] = *(const v4f*)&k_lds[lane * HD + i * 4];

    // cq_lane = k_lane . q_tl  (qrow reads uniform -> broadcast)
    v4f cacc = {0.f, 0.f, 0.f, 0.f};
    #pragma unroll
    for (int i = 0; i < 16; ++i) {
        const v4f qv = *(const v4f*)&qrow[i * 4];
        cacc = __builtin_elementwise_fma(qv, kreg[i], cacc);
    }
    const float cq = hsum4(cacc);

    // G build into gu_lds: wave w rows [16w,16w+16): G[t][lane] = k_t . k_lane
    #pragma unroll 1
    for (int t0 = 0; t0 < 16; ++t0) {
        const int t = wid * 16 + t0;
        const float* kt = &k_lds[t * HD];    // uniform -> broadcast
        v4f a = {0.f, 0.f, 0.f, 0.f};
        #pragma unroll
        for (int i = 0; i < 16; ++i) {
            const v4f kv = *(const v4f*)&kt[i * 4];
            a = __builtin_elementwise_fma(kv, kreg[i], a);
        }
        gu_lds[t * HD + lane] = hsum4(a);
    }

    // dv quarter = v_lane[16wid..16wid+16); R = 0; partial nd2
    v4f dv[4], R[4];
    v4f acc = {0.f, 0.f, 0.f, 0.f};
    #pragma unroll
    for (int i = 0; i < 4; ++i) {
        dv[i] = *(const v4f*)&v_lds[lane * HD + wid * 16 + i * 4];
        R[i]  = (v4f){0.f, 0.f, 0.f, 0.f};
        acc   = __builtin_elementwise_fma(dv[i], dv[i], acc);
    }
    pbuf[0][wid][lane] = hsum4(acc);
    int pp = 1;
    __syncthreads();                       // G + pbuf[0] visible
    float nd2 = ((pbuf[0][0][lane] + pbuf[0][1][lane]) +
                 (pbuf[0][2][lane] + pbuf[0][3][lane]));
    unsigned long long fireset = __ballot(nd2 > thr2);

    // Phase 2: fire loop (R8-verified)
    int chunk = tok_lds[lane];
    #pragma unroll 1
    for (int c = 0; c < NCH; ++c) {
        int nxt = 0;
        if (c + 1 < NCH) nxt = tok_lds[(c + 1) * 64 + lane];
        unsigned long long pend = __ballot((int)((fireset >> chunk) & 1ull));
        while (pend) {
            const int s = __builtin_ctzll(pend);
            const int t = __builtin_amdgcn_readlane(chunk, s);
            const float g   = gu_lds[t * HD + lane];
            const float cqt = bcastf(cq, t);
            const v4f gs  = {-g, -g, -g, -g};
            const v4f cqs = {cqt, cqt, cqt, cqt};
            v4f q4 = {0.f, 0.f, 0.f, 0.f};
            #pragma unroll
            for (int i = 0; i < 4; ++i) {
                v4f sve;                           // delta_t quarter (own regs)
                sve.x = bcastf(dv[i].x, t);
                sve.y = bcastf(dv[i].y, t);
                sve.z = bcastf(dv[i].z, t);
                sve.w = bcastf(dv[i].w, t);
                dv[i] = __builtin_elementwise_fma(gs, sve, dv[i]);
                R[i]  = __builtin_elementwise_fma(cqs, sve, R[i]);
                q4    = __builtin_elementwise_fma(dv[i], dv[i], q4);
            }
            pbuf[pp][wid][lane] = hsum4(q4);
            __syncthreads();                       // single barrier per fire
            nd2 = ((pbuf[pp][0][lane] + pbuf[pp][1][lane]) +
                   (pbuf[pp][2][lane] + pbuf[pp][3][lane]));
            pp ^= 1;                               // ping-pong: no 2nd barrier
            fireset = __ballot(nd2 > thr2);
            const unsigned long long above =
                (s >= 63) ? 0ull : (~0ull << (s + 1));
            pend = __ballot((int)((fireset >> chunk) & 1ull)) & above;
        }
        chunk = nxt;
    }

    // read = relu(R): wave w holds components [16wid..16wid+16) in each lane
    if (lane == 0) {
        #pragma unroll
        for (int i = 0; i < 4; ++i) {
            v4f r = R[i];
            r.x = fmaxf(r.x, 0.f); r.y = fmaxf(r.y, 0.f);
            r.z = fmaxf(r.z, 0.f); r.w = fmaxf(r.w, 0.f);
            *(v4f*)&rd_lds[wid * 16 + i * 4] = r;
        }
    }
    __syncthreads();

    // out[b][c] = sum_j rd[j] * wo[j][c] + bo[c]  — wave 0 only (lane = c)
    if (wid == 0) {
        if (bf) {
            float acc2 = __bfloat162float(((const __hip_bfloat16*)bo)[lane]);
            #pragma unroll 8
            for (int j = 0; j < HD; ++j)
                acc2 = fmaf(rd_lds[j],
                    __bfloat162float(((const __hip_bfloat16*)wo)[j * HD + lane]),
                    acc2);
            ((__hip_bfloat16*)out)[b * HD + lane] = __float2bfloat16(acc2);
        } else {
            float acc2 = ((const float*)bo)[lane];
            #pragma unroll 8
            for (int j = 0; j < HD; ++j)
                acc2 = fmaf(rd_lds[j], ((const float*)wo)[j * HD + lane], acc2);
            ((float*)out)[b * HD + lane] = acc2;
        }
    }
}

extern "C" void kernel_launch(void* const* d_in, const int* in_sizes, int n_in,
                              void* d_out, int out_size, void* d_ws, size_t ws_size,
                              hipStream_t stream) {
    const int* x      = (const int*)d_in[0];
    const void* embed = d_in[1];
    const void* w1    = d_in[2];
    const void* b1    = d_in[3];
    const void* w2    = d_in[4];
    const void* b2    = d_in[5];
    const void* ln_g  = d_in[6];
    const void* ln_b  = d_in[7];
    const void* wk    = d_in[8];
    const void* wvp   = d_in[9];
    const void* wq    = d_in[10];
    const void* wo    = d_in[11];
    const void* bo    = d_in[12];

    fused_kernel<<<NB, 256, 0, stream>>>(x, embed, w1, b1, w2, b2, ln_g, ln_b,
                                         wk, wvp, wq, wo, bo, d_out);
}